// Round 1
// baseline (544.301 us; speedup 1.0000x reference)
//
#include <hip/hip_runtime.h>

// ---------------------------------------------------------------------------
// EncoderDecoderAttentionHead: z = softmax((x@Wq^T+bq) @ (enc0@x)^T / sqrt(D)) @ (enc1@x)
// S = T = 4096, D = 2048. All matmuls run as bf16 MFMA (16x16x32), fp32 accum.
// Every GEMM is in A @ B^T form (both operands row-major, K contiguous):
//   q  [S,D] = x_bf  [S,D] @ Wq_bf [D,D]^T  (+bq)
//   k  [T,D] = enc0  [T,S] @ xT    [D,S]^T
//   vT [D,T] = xT    [D,S] @ enc1  [T,S]^T
//   e  [S,T] = q_bf  [S,D] @ k_bf  [T,D]^T  * 1/sqrt(D)   (fp32 out)
//   z  [S,D] = a_bf  [S,T] @ vT    [D,T]^T                 (fp32 out -> d_out)
// ---------------------------------------------------------------------------

typedef __attribute__((ext_vector_type(8))) __bf16 bf16x8;
typedef __attribute__((ext_vector_type(4))) float f32x4;
typedef __attribute__((ext_vector_type(4))) unsigned short ushort4v;
typedef __attribute__((ext_vector_type(8))) unsigned short ushort8v;

#define S_DIM 4096
#define T_DIM 4096
#define D_DIM 2048

__device__ __forceinline__ unsigned short f2bf(float f) {
    unsigned int u = __float_as_uint(f);
    u += 0x7fffu + ((u >> 16) & 1u);   // round-to-nearest-even
    return (unsigned short)(u >> 16);
}

// ---- f32 -> bf16 convert, 8 elems/thread, grid-stride ----------------------
__global__ __launch_bounds__(256)
void k_convert(const float* __restrict__ in, unsigned short* __restrict__ out, long n) {
    long i = ((long)blockIdx.x * blockDim.x + threadIdx.x) * 8;
    const long stride = (long)gridDim.x * blockDim.x * 8;
    for (; i < n; i += stride) {
        float4 a = *(const float4*)(in + i);
        float4 b = *(const float4*)(in + i + 4);
        ushort8v o;
        o[0] = f2bf(a.x); o[1] = f2bf(a.y); o[2] = f2bf(a.z); o[3] = f2bf(a.w);
        o[4] = f2bf(b.x); o[5] = f2bf(b.y); o[6] = f2bf(b.z); o[7] = f2bf(b.w);
        *(ushort8v*)(out + i) = o;
    }
}

// ---- transpose f32 [R][C] -> bf16 [C][R] -----------------------------------
__global__ __launch_bounds__(256)
void k_transpose(const float* __restrict__ in, unsigned short* __restrict__ out,
                 int R, int C) {
    __shared__ float tile[32][33];
    const int bx = blockIdx.x * 32;   // col base in C
    const int by = blockIdx.y * 32;   // row base in R
    const int tx = threadIdx.x;       // 0..31
    const int ty = threadIdx.y;       // 0..7
    #pragma unroll
    for (int i = 0; i < 32; i += 8)
        tile[ty + i][tx] = in[(long)(by + ty + i) * C + bx + tx];
    __syncthreads();
    #pragma unroll
    for (int i = 0; i < 32; i += 8)
        out[(long)(bx + ty + i) * R + by + tx] = f2bf(tile[tx][ty + i]);
}

// ---- bf16 GEMM, C[M,N] = alpha * A[M,K] @ B[N,K]^T (+bias[col]) -------------
// m97 structure: 128x128 tile, BK=32, 4 waves (2x2), 4x4 16x16x32 frags/wave,
// global_load_lds width-16 staging into linear LDS.
template<int OUT_BF16, int HAS_BIAS>
__global__ __launch_bounds__(256)
void k_gemm_bt(const unsigned short* __restrict__ A,
               const unsigned short* __restrict__ B,
               const float* __restrict__ bias,
               void* __restrict__ C,
               int M, int N, int K, float alpha) {
    __shared__ __align__(16) unsigned short As[128 * 32];
    __shared__ __align__(16) unsigned short Bs[128 * 32];

    const int t = threadIdx.x;
    const int l = t & 63;
    const int w = t >> 6;
    const int wr = w >> 1;            // 0..1
    const int wc = w & 1;             // 0..1
    const long brow = (long)blockIdx.y * 128;
    const long bcol = (long)blockIdx.x * 128;

    f32x4 acc[4][4] = {};

    // staging: thread t loads 16B: row = t/4 (+64 for pass 1), chunk = t%4
    const int srow   = t >> 2;        // 0..63
    const int schunk = (t & 3) * 8;   // element offset within BK=32
    const unsigned short* gA0 = A + (brow + srow)      * (long)K + schunk;
    const unsigned short* gA1 = A + (brow + 64 + srow) * (long)K + schunk;
    const unsigned short* gB0 = B + (bcol + srow)      * (long)K + schunk;
    const unsigned short* gB1 = B + (bcol + 64 + srow) * (long)K + schunk;

    const int rA = wr * 64 + (l & 15);
    const int rB = wc * 64 + (l & 15);
    const int kh = (l >> 4) * 8;

    for (int k0 = 0; k0 < K; k0 += 32) {
        __builtin_amdgcn_global_load_lds(
            (__attribute__((address_space(1))) void*)(void*)(gA0 + k0),
            (__attribute__((address_space(3))) void*)(As + t * 8), 16, 0, 0);
        __builtin_amdgcn_global_load_lds(
            (__attribute__((address_space(1))) void*)(void*)(gA1 + k0),
            (__attribute__((address_space(3))) void*)(As + 2048 + t * 8), 16, 0, 0);
        __builtin_amdgcn_global_load_lds(
            (__attribute__((address_space(1))) void*)(void*)(gB0 + k0),
            (__attribute__((address_space(3))) void*)(Bs + t * 8), 16, 0, 0);
        __builtin_amdgcn_global_load_lds(
            (__attribute__((address_space(1))) void*)(void*)(gB1 + k0),
            (__attribute__((address_space(3))) void*)(Bs + 2048 + t * 8), 16, 0, 0);
        __syncthreads();

        bf16x8 af[4], bfr[4];
        #pragma unroll
        for (int m = 0; m < 4; ++m)
            af[m] = *(const bf16x8*)(As + (rA + m * 16) * 32 + kh);
        #pragma unroll
        for (int n = 0; n < 4; ++n)
            bfr[n] = *(const bf16x8*)(Bs + (rB + n * 16) * 32 + kh);
        #pragma unroll
        for (int m = 0; m < 4; ++m)
            #pragma unroll
            for (int n = 0; n < 4; ++n)
                acc[m][n] = __builtin_amdgcn_mfma_f32_16x16x32_bf16(
                    af[m], bfr[n], acc[m][n], 0, 0, 0);
        __syncthreads();
    }

    // epilogue: C/D layout col = lane&15, row = (lane>>4)*4 + reg
    const long crow0 = brow + wr * 64 + (l >> 4) * 4;
    const long ccol0 = bcol + wc * 64 + (l & 15);
    #pragma unroll
    for (int n = 0; n < 4; ++n) {
        const long col = ccol0 + n * 16;
        const float bb = HAS_BIAS ? bias[col] : 0.0f;
        #pragma unroll
        for (int m = 0; m < 4; ++m) {
            #pragma unroll
            for (int r = 0; r < 4; ++r) {
                const long row = crow0 + m * 16 + r;
                const float v = acc[m][n][r] * alpha + bb;
                if (OUT_BF16)
                    ((unsigned short*)C)[row * N + col] = f2bf(v);
                else
                    ((float*)C)[row * N + col] = v;
            }
        }
    }
}

// ---- row softmax: e [S][T] f32 -> a [S][T] bf16 -----------------------------
__global__ __launch_bounds__(256)
void k_softmax(const float* __restrict__ E, unsigned short* __restrict__ A, int T) {
    const long row = blockIdx.x;
    const float* er = E + row * (long)T;
    const int t = threadIdx.x;
    const int l = t & 63;
    const int w = t >> 6;

    float4 v[4];
    float m = -3.4e38f;
    #pragma unroll
    for (int j = 0; j < 4; ++j) {
        v[j] = *(const float4*)(er + j * 1024 + t * 4);
        m = fmaxf(m, fmaxf(fmaxf(v[j].x, v[j].y), fmaxf(v[j].z, v[j].w)));
    }
    #pragma unroll
    for (int o = 32; o > 0; o >>= 1) m = fmaxf(m, __shfl_xor(m, o));

    __shared__ float redm[4];
    __shared__ float reds[4];
    if (l == 0) redm[w] = m;
    __syncthreads();
    m = fmaxf(fmaxf(redm[0], redm[1]), fmaxf(redm[2], redm[3]));

    float s = 0.f;
    #pragma unroll
    for (int j = 0; j < 4; ++j) {
        v[j].x = __expf(v[j].x - m); s += v[j].x;
        v[j].y = __expf(v[j].y - m); s += v[j].y;
        v[j].z = __expf(v[j].z - m); s += v[j].z;
        v[j].w = __expf(v[j].w - m); s += v[j].w;
    }
    #pragma unroll
    for (int o = 32; o > 0; o >>= 1) s += __shfl_xor(s, o);
    if (l == 0) reds[w] = s;
    __syncthreads();
    s = reds[0] + reds[1] + reds[2] + reds[3];
    const float inv = 1.0f / s;

    unsigned short* ar = A + row * (long)T;
    #pragma unroll
    for (int j = 0; j < 4; ++j) {
        ushort4v o4;
        o4[0] = f2bf(v[j].x * inv);
        o4[1] = f2bf(v[j].y * inv);
        o4[2] = f2bf(v[j].z * inv);
        o4[3] = f2bf(v[j].w * inv);
        *(ushort4v*)(ar + j * 1024 + t * 4) = o4;
    }
}

// ---------------------------------------------------------------------------
extern "C" void kernel_launch(void* const* d_in, const int* in_sizes, int n_in,
                              void* d_out, int out_size, void* d_ws, size_t ws_size,
                              hipStream_t stream) {
    const float* x   = (const float*)d_in[0];   // [S][D]
    const float* enc = (const float*)d_in[1];   // [2][T][S]
    const float* Wq  = (const float*)d_in[2];   // [D][D]
    const float* bq  = (const float*)d_in[3];   // [D]
    float* out = (float*)d_out;                 // [S][D]
    char* ws = (char*)d_ws;

    // workspace layout (bytes); e overlaps enc_bf (dead after vT GEMM). 184 MB.
    unsigned short* xT    = (unsigned short*)(ws);                 // [D][S] 16MB
    unsigned short* xbf   = (unsigned short*)(ws + (16L << 20));   // [S][D] 16MB
    unsigned short* wqbf  = (unsigned short*)(ws + (32L << 20));   // [D][D]  8MB
    unsigned short* qbf   = (unsigned short*)(ws + (40L << 20));   // [S][D] 16MB
    unsigned short* kbf   = (unsigned short*)(ws + (56L << 20));   // [T][D] 16MB
    unsigned short* vT    = (unsigned short*)(ws + (72L << 20));   // [D][T] 16MB
    unsigned short* encbf = (unsigned short*)(ws + (88L << 20));   // [2][T][S] 64MB
    float*          e     = (float*)(ws + (88L << 20));            // [S][T] 64MB (reuse)
    unsigned short* abf   = (unsigned short*)(ws + (152L << 20));  // [S][T] 32MB

    // 1) converts + transpose
    k_convert<<<4096, 256, 0, stream>>>(x,   xbf,   (long)S_DIM * D_DIM);
    k_convert<<<4096, 256, 0, stream>>>(Wq,  wqbf,  (long)D_DIM * D_DIM);
    k_convert<<<4096, 256, 0, stream>>>(enc, encbf, 2L * T_DIM * S_DIM);
    k_transpose<<<dim3(D_DIM / 32, S_DIM / 32), dim3(32, 8), 0, stream>>>(x, xT, S_DIM, D_DIM);

    // 2) q = x @ Wq^T + bq          [S,D]
    k_gemm_bt<1, 1><<<dim3(D_DIM / 128, S_DIM / 128), 256, 0, stream>>>(
        xbf, wqbf, bq, qbf, S_DIM, D_DIM, D_DIM, 1.0f);
    // 3) k = enc0 @ x = enc0 @ xT^T [T,D]
    k_gemm_bt<1, 0><<<dim3(D_DIM / 128, T_DIM / 128), 256, 0, stream>>>(
        encbf, xT, nullptr, kbf, T_DIM, D_DIM, S_DIM, 1.0f);
    // 4) vT = xT @ enc1^T           [D,T]
    k_gemm_bt<1, 0><<<dim3(T_DIM / 128, D_DIM / 128), 256, 0, stream>>>(
        xT, encbf + (long)T_DIM * S_DIM, nullptr, vT, D_DIM, T_DIM, S_DIM, 1.0f);
    // 5) e = q @ k^T / sqrt(D)      [S,T] fp32 (overwrites enc_bf region)
    k_gemm_bt<0, 0><<<dim3(T_DIM / 128, S_DIM / 128), 256, 0, stream>>>(
        qbf, kbf, nullptr, e, S_DIM, T_DIM, D_DIM, 0.022097086912079608f);
    // 6) a = softmax(e, axis=1) -> bf16
    k_softmax<<<S_DIM, 256, 0, stream>>>(e, abf, T_DIM);
    // 7) z = a @ v = a @ vT^T       [S,D] fp32 -> d_out
    k_gemm_bt<0, 0><<<dim3(D_DIM / 128, S_DIM / 128), 256, 0, stream>>>(
        abf, vT, nullptr, out, S_DIM, D_DIM, T_DIM, 1.0f);
}

// Round 2
// 409.215 us; speedup vs baseline: 1.3301x; 1.3301x over previous
//
#include <hip/hip_runtime.h>

// ---------------------------------------------------------------------------
// EncoderDecoderAttentionHead. All GEMMs as A[M,K] @ B[N,K]^T, bf16 MFMA.
// 8-phase-style pipelined GEMM: BM=128, BN=256, BK=64, 8 waves (2Mx4N),
// triple-buffered LDS (3x48KB), counted vmcnt(6), chunk-XOR LDS swizzle,
// setprio around MFMA clusters. All 5 GEMM shapes give grids of 256/512
// blocks (1 block/CU).
// ---------------------------------------------------------------------------

typedef __attribute__((ext_vector_type(8))) __bf16 bf16x8;
typedef __attribute__((ext_vector_type(4))) float f32x4;
typedef __attribute__((ext_vector_type(4))) unsigned short ushort4v;
typedef __attribute__((ext_vector_type(8))) unsigned short ushort8v;

#define S_DIM 4096
#define T_DIM 4096
#define D_DIM 2048

#define LDSA_BYTES (128 * 64 * 2)                 // 16 KB A tile
#define LDSB_BYTES (256 * 64 * 2)                 // 32 KB B tile
#define BUF_BYTES  (LDSA_BYTES + LDSB_BYTES)      // 48 KB per K-tile
#define SMEM_BYTES (3 * BUF_BYTES)                // 144 KB, triple-buffered

__device__ __forceinline__ unsigned short f2bf(float f) {
    unsigned int u = __float_as_uint(f);
    u += 0x7fffu + ((u >> 16) & 1u);
    return (unsigned short)(u >> 16);
}

__device__ __forceinline__ void block_sync() {
    __builtin_amdgcn_sched_barrier(0);
    __builtin_amdgcn_s_barrier();
    __builtin_amdgcn_sched_barrier(0);
}

#define GL(gptr, sptr)                                                        \
    __builtin_amdgcn_global_load_lds(                                         \
        (__attribute__((address_space(1))) void*)(void*)(gptr),               \
        (__attribute__((address_space(3))) void*)(sptr), 16, 0, 0)

// ---- f32 -> bf16 convert ---------------------------------------------------
__global__ __launch_bounds__(256)
void k_convert(const float* __restrict__ in, unsigned short* __restrict__ out, long n) {
    long i = ((long)blockIdx.x * blockDim.x + threadIdx.x) * 8;
    const long stride = (long)gridDim.x * blockDim.x * 8;
    for (; i < n; i += stride) {
        float4 a = *(const float4*)(in + i);
        float4 b = *(const float4*)(in + i + 4);
        ushort8v o;
        o[0] = f2bf(a.x); o[1] = f2bf(a.y); o[2] = f2bf(a.z); o[3] = f2bf(a.w);
        o[4] = f2bf(b.x); o[5] = f2bf(b.y); o[6] = f2bf(b.z); o[7] = f2bf(b.w);
        *(ushort8v*)(out + i) = o;
    }
}

// ---- transpose f32 [R][C] -> bf16 [C][R] -----------------------------------
__global__ __launch_bounds__(256)
void k_transpose(const float* __restrict__ in, unsigned short* __restrict__ out,
                 int R, int C) {
    __shared__ float tile[32][33];
    const int bx = blockIdx.x * 32;
    const int by = blockIdx.y * 32;
    const int tx = threadIdx.x;
    const int ty = threadIdx.y;
    #pragma unroll
    for (int i = 0; i < 32; i += 8)
        tile[ty + i][tx] = in[(long)(by + ty + i) * C + bx + tx];
    __syncthreads();
    #pragma unroll
    for (int i = 0; i < 32; i += 8)
        out[(long)(bx + ty + i) * R + by + tx] = f2bf(tile[tx][ty + i]);
}

// ---- pipelined bf16 GEMM, C[M,N] = alpha*A[M,K]@B[N,K]^T (+bias[col]) ------
template<int OUT_BF16, int HAS_BIAS>
__global__ __launch_bounds__(512, 2)
void k_gemm8p(const unsigned short* __restrict__ A,
              const unsigned short* __restrict__ B,
              const float* __restrict__ bias,
              void* __restrict__ C,
              int M, int N, int K, float alpha) {
    extern __shared__ __align__(16) char smem[];
    const int tid = threadIdx.x;
    const int l = tid & 63;
    const int w = tid >> 6;
    const int wr = w >> 2;            // 0..1 (M waves)
    const int wc = w & 3;             // 0..3 (N waves)
    const long brow = (long)blockIdx.y * 128;
    const long bcol = (long)blockIdx.x * 256;
    const int NT = K >> 6;

    const unsigned short* Ab = A + brow * (long)K;
    const unsigned short* Bb = B + bcol * (long)K;

    // ---- staging geometry: linear LDS chunk q; global chunk cg = (q&7)^(row&7)
    int aoff[2], ldsa[2];
    #pragma unroll
    for (int j = 0; j < 2; ++j) {
        int q = (w * 2 + j) * 64 + l;      // 0..1023  -> [128 rows][8 chunks]
        int r = q >> 3;
        int cg = (q & 7) ^ (r & 7);
        aoff[j] = r * K + cg * 8;
        ldsa[j] = q * 16;
    }
    int boff[4], ldsb[4];
    #pragma unroll
    for (int j = 0; j < 4; ++j) {
        int q = (w * 4 + j) * 64 + l;      // 0..2047  -> [256 rows][8 chunks]
        int r = q >> 3;
        int cg = (q & 7) ^ (r & 7);
        boff[j] = r * K + cg * 8;
        ldsb[j] = LDSA_BYTES + q * 16;
    }

    // ---- ds_read geometry (swizzled): chunk_swz = (ks*4 + l>>4) ^ (l&7)
    const int cs0 = (((l >> 4) ^ (l & 7)) << 4);
    const int cs1 = ((((l >> 4) + 4) ^ (l & 7)) << 4);
    const int arB = (wr * 64 + (l & 15)) * 128;
    const int brB = LDSA_BYTES + (wc * 64 + (l & 15)) * 128;

    char* bcur = smem;
    char* bnx  = smem + BUF_BYTES;
    char* bn2  = smem + 2 * BUF_BYTES;

    // ---- prologue: tile 0 -> buf0, tile 1 -> buf1; drain tile 0 ------------
    {
        GL(Ab + aoff[0], bcur + ldsa[0]);
        GL(Ab + aoff[1], bcur + ldsa[1]);
        GL(Bb + boff[0], bcur + ldsb[0]);
        GL(Bb + boff[1], bcur + ldsb[1]);
        GL(Bb + boff[2], bcur + ldsb[2]);
        GL(Bb + boff[3], bcur + ldsb[3]);
        GL(Ab + 64 + aoff[0], bnx + ldsa[0]);
        GL(Ab + 64 + aoff[1], bnx + ldsa[1]);
        GL(Bb + 64 + boff[0], bnx + ldsb[0]);
        GL(Bb + 64 + boff[1], bnx + ldsb[1]);
        GL(Bb + 64 + boff[2], bnx + ldsb[2]);
        GL(Bb + 64 + boff[3], bnx + ldsb[3]);
        asm volatile("s_waitcnt vmcnt(6)" ::: "memory");
    }
    block_sync();

    f32x4 acc[4][4] = {};

    #define RDA(m, ks) (*(const bf16x8*)(bcur + arB + (m) * 2048 + ((ks) ? cs1 : cs0)))
    #define RDB(n, ks) (*(const bf16x8*)(bcur + brB + (n) * 2048 + ((ks) ? cs1 : cs0)))

    for (int t = 0; t < NT; ++t) {
        const long kk = (long)(t + 2) << 6;
        // ---------------- phase A: m=0,1 x n=0..3 ----------------
        bf16x8 bfrag[4][2];
        #pragma unroll
        for (int n = 0; n < 4; ++n) {
            bfrag[n][0] = RDB(n, 0);
            bfrag[n][1] = RDB(n, 1);
        }
        bf16x8 afrag[2][2];
        #pragma unroll
        for (int m = 0; m < 2; ++m) {
            afrag[m][0] = RDA(m, 0);
            afrag[m][1] = RDA(m, 1);
        }
        if (t + 2 < NT) {
            GL(Ab + kk + aoff[0], bn2 + ldsa[0]);
            GL(Ab + kk + aoff[1], bn2 + ldsa[1]);
            GL(Bb + kk + boff[0], bn2 + ldsb[0]);
        }
        block_sync();
        __builtin_amdgcn_s_setprio(1);
        #pragma unroll
        for (int ks = 0; ks < 2; ++ks)
            #pragma unroll
            for (int m = 0; m < 2; ++m)
                #pragma unroll
                for (int n = 0; n < 4; ++n)
                    acc[m][n] = __builtin_amdgcn_mfma_f32_16x16x32_bf16(
                        afrag[m][ks], bfrag[n][ks], acc[m][n], 0, 0, 0);
        __builtin_amdgcn_s_setprio(0);
        block_sync();
        // ---------------- phase B: m=2,3 x n=0..3 ----------------
        bf16x8 afrag2[2][2];
        #pragma unroll
        for (int m = 0; m < 2; ++m) {
            afrag2[m][0] = RDA(m + 2, 0);
            afrag2[m][1] = RDA(m + 2, 1);
        }
        if (t + 2 < NT) {
            GL(Bb + kk + boff[1], bn2 + ldsb[1]);
            GL(Bb + kk + boff[2], bn2 + ldsb[2]);
            GL(Bb + kk + boff[3], bn2 + ldsb[3]);
        }
        block_sync();
        __builtin_amdgcn_s_setprio(1);
        #pragma unroll
        for (int ks = 0; ks < 2; ++ks)
            #pragma unroll
            for (int m = 0; m < 2; ++m)
                #pragma unroll
                for (int n = 0; n < 4; ++n)
                    acc[m + 2][n] = __builtin_amdgcn_mfma_f32_16x16x32_bf16(
                        afrag2[m][ks], bfrag[n][ks], acc[m + 2][n], 0, 0, 0);
        __builtin_amdgcn_s_setprio(0);
        if (t + 2 < NT) {
            asm volatile("s_waitcnt vmcnt(6)" ::: "memory");   // tile t+1 landed
        } else if (t + 1 < NT) {
            asm volatile("s_waitcnt vmcnt(0)" ::: "memory");   // last tile landed
        }
        block_sync();
        char* tmp = bcur; bcur = bnx; bnx = bn2; bn2 = tmp;
    }
    #undef RDA
    #undef RDB

    // ---- epilogue: C/D layout col = lane&15, row = (lane>>4)*4 + reg -------
    const long crow0 = brow + wr * 64 + (l >> 4) * 4;
    const long ccol0 = bcol + wc * 64 + (l & 15);
    #pragma unroll
    for (int n = 0; n < 4; ++n) {
        const long col = ccol0 + n * 16;
        const float bb = HAS_BIAS ? bias[col] : 0.0f;
        #pragma unroll
        for (int m = 0; m < 4; ++m) {
            #pragma unroll
            for (int r = 0; r < 4; ++r) {
                const long row = crow0 + m * 16 + r;
                const float v = acc[m][n][r] * alpha + bb;
                if (OUT_BF16)
                    ((unsigned short*)C)[row * N + col] = f2bf(v);
                else
                    ((float*)C)[row * N + col] = v;
            }
        }
    }
}

// ---- row softmax: e [S][T] f32 -> a [S][T] bf16 -----------------------------
__global__ __launch_bounds__(256)
void k_softmax(const float* __restrict__ E, unsigned short* __restrict__ A, int T) {
    const long row = blockIdx.x;
    const float* er = E + row * (long)T;
    const int t = threadIdx.x;
    const int l = t & 63;
    const int w = t >> 6;

    float4 v[4];
    float m = -3.4e38f;
    #pragma unroll
    for (int j = 0; j < 4; ++j) {
        v[j] = *(const float4*)(er + j * 1024 + t * 4);
        m = fmaxf(m, fmaxf(fmaxf(v[j].x, v[j].y), fmaxf(v[j].z, v[j].w)));
    }
    #pragma unroll
    for (int o = 32; o > 0; o >>= 1) m = fmaxf(m, __shfl_xor(m, o));

    __shared__ float redm[4];
    __shared__ float reds[4];
    if (l == 0) redm[w] = m;
    __syncthreads();
    m = fmaxf(fmaxf(redm[0], redm[1]), fmaxf(redm[2], redm[3]));

    float s = 0.f;
    #pragma unroll
    for (int j = 0; j < 4; ++j) {
        v[j].x = __expf(v[j].x - m); s += v[j].x;
        v[j].y = __expf(v[j].y - m); s += v[j].y;
        v[j].z = __expf(v[j].z - m); s += v[j].z;
        v[j].w = __expf(v[j].w - m); s += v[j].w;
    }
    #pragma unroll
    for (int o = 32; o > 0; o >>= 1) s += __shfl_xor(s, o);
    if (l == 0) reds[w] = s;
    __syncthreads();
    s = reds[0] + reds[1] + reds[2] + reds[3];
    const float inv = 1.0f / s;

    unsigned short* ar = A + row * (long)T;
    #pragma unroll
    for (int j = 0; j < 4; ++j) {
        ushort4v o4;
        o4[0] = f2bf(v[j].x * inv);
        o4[1] = f2bf(v[j].y * inv);
        o4[2] = f2bf(v[j].z * inv);
        o4[3] = f2bf(v[j].w * inv);
        *(ushort4v*)(ar + j * 1024 + t * 4) = o4;
    }
}

// ---------------------------------------------------------------------------
extern "C" void kernel_launch(void* const* d_in, const int* in_sizes, int n_in,
                              void* d_out, int out_size, void* d_ws, size_t ws_size,
                              hipStream_t stream) {
    const float* x   = (const float*)d_in[0];   // [S][D]
    const float* enc = (const float*)d_in[1];   // [2][T][S]
    const float* Wq  = (const float*)d_in[2];   // [D][D]
    const float* bq  = (const float*)d_in[3];   // [D]
    float* out = (float*)d_out;                 // [S][D]
    char* ws = (char*)d_ws;

    unsigned short* xT    = (unsigned short*)(ws);                 // [D][S] 16MB
    unsigned short* xbf   = (unsigned short*)(ws + (16L << 20));   // [S][D] 16MB
    unsigned short* wqbf  = (unsigned short*)(ws + (32L << 20));   // [D][D]  8MB
    unsigned short* qbf   = (unsigned short*)(ws + (40L << 20));   // [S][D] 16MB
    unsigned short* kbf   = (unsigned short*)(ws + (56L << 20));   // [T][D] 16MB
    unsigned short* vT    = (unsigned short*)(ws + (72L << 20));   // [D][T] 16MB
    unsigned short* encbf = (unsigned short*)(ws + (88L << 20));   // [2][T][S] 64MB
    float*          e     = (float*)(ws + (88L << 20));            // [S][T] 64MB (reuse)
    unsigned short* abf   = (unsigned short*)(ws + (152L << 20));  // [S][T] 32MB

    k_convert<<<4096, 256, 0, stream>>>(x,   xbf,   (long)S_DIM * D_DIM);
    k_convert<<<4096, 256, 0, stream>>>(Wq,  wqbf,  (long)D_DIM * D_DIM);
    k_convert<<<4096, 256, 0, stream>>>(enc, encbf, 2L * T_DIM * S_DIM);
    k_transpose<<<dim3(D_DIM / 32, S_DIM / 32), dim3(32, 8), 0, stream>>>(x, xT, S_DIM, D_DIM);

    #define LAUNCH_G(OB, HB, Ap, Bp, biasp, Cp, M_, N_, K_, al)                          \
        do {                                                                             \
            hipFuncSetAttribute((const void*)k_gemm8p<OB, HB>,                           \
                                hipFuncAttributeMaxDynamicSharedMemorySize, SMEM_BYTES); \
            k_gemm8p<OB, HB><<<dim3((N_) / 256, (M_) / 128), 512, SMEM_BYTES, stream>>>( \
                Ap, Bp, biasp, Cp, M_, N_, K_, al);                                      \
        } while (0)

    // q = x @ Wq^T + bq           [S,D]
    LAUNCH_G(1, 1, xbf, wqbf, bq, qbf, S_DIM, D_DIM, D_DIM, 1.0f);
    // k = enc0 @ xT^T             [T,D]
    LAUNCH_G(1, 0, encbf, xT, nullptr, kbf, T_DIM, D_DIM, S_DIM, 1.0f);
    // vT = xT @ enc1^T            [D,T]
    LAUNCH_G(1, 0, xT, encbf + (long)T_DIM * S_DIM, nullptr, vT, D_DIM, T_DIM, S_DIM, 1.0f);
    // e = q @ k^T / sqrt(D)       [S,T] fp32
    LAUNCH_G(0, 0, qbf, kbf, nullptr, e, S_DIM, T_DIM, D_DIM, 0.022097086912079608f);
    // a = softmax(e)              [S,T] bf16
    k_softmax<<<S_DIM, 256, 0, stream>>>(e, abf, T_DIM);
    // z = a @ vT^T                [S,D] fp32 -> d_out
    LAUNCH_G(0, 0, abf, vT, nullptr, out, S_DIM, D_DIM, T_DIM, 1.0f);
}